// Round 5
// baseline (930.481 us; speedup 1.0000x reference)
//
#include <hip/hip_runtime.h>

#define HD 256
#define KD 512

typedef _Float16 half8 __attribute__((ext_vector_type(8)));
typedef _Float16 half4v __attribute__((ext_vector_type(4)));
typedef float floatx4 __attribute__((ext_vector_type(4)));

__device__ __forceinline__ float sigmf_(float x) { return 1.f / (1.f + __expf(-x)); }
__device__ __forceinline__ float tanhf_(float x) {
  x = fminf(fmaxf(x, -15.f), 15.f);
  float e = __expf(2.f * x);
  return (e - 1.f) / (e + 1.f);
}

// ---------------------------------------------------------------------------
// prep (parallel, 16 blocks): gate bias sums, leaf csum (=2*c_leaf), and
// leaf-level folded bias: bias2[g][n] = bsum[g][n] + W_g[n][0:256]·(2*h_leaf)
// block id = (gate g = bid>>2, col-quarter q = bid&3); thread = (n_local, k-quarter)
// ---------------------------------------------------------------------------
__global__ void prep_kernel(const float* __restrict__ bf_, const float* __restrict__ b_f,
                            const float* __restrict__ bi_, const float* __restrict__ b_i,
                            const float* __restrict__ bu_, const float* __restrict__ b_u,
                            const float* __restrict__ bo_, const float* __restrict__ b_o,
                            const float* __restrict__ Wf, const float* __restrict__ Wi,
                            const float* __restrict__ Wu, const float* __restrict__ Wo,
                            float* __restrict__ bsum, float* __restrict__ bias2,
                            float* __restrict__ cleaf2)
{
  __shared__ float hl2[HD];
  __shared__ float part[64][4];
  const int t = threadIdx.x;
  float sf = bf_[t] + b_f[t];
  float si = bi_[t] + b_i[t];
  float su = bu_[t] + b_u[t];
  float so = bo_[t] + b_o[t];
  float ig = 1.f / (1.f + expf(-si));
  float uu = tanhf(su);
  float cl = ig * uu;
  float hl = (1.f / (1.f + expf(-so))) * tanhf(cl);
  hl2[t] = 2.f * hl;
  if (blockIdx.x == 0) {
    bsum[t] = sf; bsum[HD + t] = si; bsum[2 * HD + t] = su; bsum[3 * HD + t] = so;
    cleaf2[t] = cl + cl;
  }
  __syncthreads();
  const int g = blockIdx.x >> 2, q = blockIdx.x & 3;
  const int nl = t >> 2, kq = t & 3;
  const float* Wg = (g == 0) ? Wf : (g == 1) ? Wi : (g == 2) ? Wu : Wo;
  const float* w = Wg + (long)(q * 64 + nl) * KD + kq * 64;
  float s = 0.f;
  for (int k = 0; k < 64; k += 4) {
    floatx4 wv = *(const floatx4*)(w + k);
    floatx4 hv = *(const floatx4*)(&hl2[kq * 64 + k]);
    s += wv[0] * hv[0] + wv[1] * hv[1] + wv[2] * hv[2] + wv[3] * hv[3];
  }
  part[nl][kq] = s;
  __syncthreads();
  if (kq == 0) {
    const int n = q * 64 + nl;
    float tot = part[nl][0] + part[nl][1] + part[nl][2] + part[nl][3];
    float bg = (g == 0) ? (bf_[n] + b_f[n]) : (g == 1) ? (bi_[n] + b_i[n])
             : (g == 2) ? (bu_[n] + b_u[n]) : (bo_[n] + b_o[n]);
    bias2[g * HD + n] = bg + tot;
  }
}

// ---------------------------------------------------------------------------
// convert the 4 gate weights (fp32, [256][512]) to f16 packed [g][256][512]
// ---------------------------------------------------------------------------
__global__ void wcvt_kernel(const float* __restrict__ Wf, const float* __restrict__ Wi,
                            const float* __restrict__ Wu, const float* __restrict__ Wo,
                            _Float16* __restrict__ Wh)
{
  int idx = (blockIdx.x * 256 + threadIdx.x) * 4;
  int g = idx >> 17;
  int rem = idx & ((1 << 17) - 1);
  const float* src = (g == 0) ? Wf : (g == 1) ? Wi : (g == 2) ? Wu : Wo;
  floatx4 v = *(const floatx4*)(src + rem);
  half4v o;
  o[0] = (_Float16)v[0]; o[1] = (_Float16)v[1]; o[2] = (_Float16)v[2]; o[3] = (_Float16)v[3];
  *(half4v*)(Wh + idx) = o;
}

// ---------------------------------------------------------------------------
// level kernel (levels 8..5).
// 512 thr = 8 waves; wave = one 16-row slab; each wave computes ALL 4 gates
// over 64 cols -> per-lane has all gate z's for a cell, epilogue needs no
// LDS exchange/barriers. Block = 128 rows; grid = (2^l, 4), n0=blockIdx.y*64.
// Interfaces PRE-PAIR-SUMMED: hsum_in[m]=h[2m]+h[2m+1] (f16), csum_in[m]=
// c[2m]+c[2m+1] (f32); outputs the same for the parent level.
// leaf: skip h chunk (folded into bias2), csum_in = cleaf2 (256-vec broadcast).
// acc indexed ONLY by compile-time constants (runtime index -> scratch spill).
// ---------------------------------------------------------------------------
__global__ __launch_bounds__(512, 2)
void level_kernel(const _Float16* __restrict__ hsum_in,
                  const float* __restrict__ csum_in,
                  const float* __restrict__ embed,
                  const _Float16* __restrict__ Wh,
                  const float* __restrict__ bias,
                  _Float16* __restrict__ hsum_out,
                  float* __restrict__ csum_out,
                  int l, int leaf)
{
  __shared__ _Float16 As[128][256];   // one K-chunk, XOR-swizzled 16B granules

  const int cnt = 1 << l;
  const int csoff = (2 << l) - 1;
  const int m0 = blockIdx.x * 128;
  const int n0 = blockIdx.y * 64;
  const int t = threadIdx.x;
  const int wave = t >> 6;
  const int lane = t & 63;
  const int lm = lane & 15;
  const int quad = lane >> 4;

  floatx4 acc[4][4] = {};             // [gate][col-tile]

  // staging mapping: row sr = t>>2 (0..127), k-quarter s4 = t&3
  const int sr = t >> 2;
  const int s4 = t & 3;

  const int arow = wave * 16 + lm;    // A-fragment row for this lane
  const int asw = arow & 7;

  auto gemm_chunk = [&](int kbase) {
#pragma unroll
    for (int ks = 0; ks < 8; ++ks) {
      half8 afr = *(const half8*)(&As[arow][(((ks * 4 + quad) ^ asw) * 8)]);
#pragma unroll
      for (int g = 0; g < 4; ++g) {
        half8 bfr[4];
#pragma unroll
        for (int nt = 0; nt < 4; ++nt)
          bfr[nt] = *(const half8*)(Wh + (long)(g * HD + n0 + nt * 16 + lm) * KD
                                    + kbase + ks * 32 + quad * 8);
#pragma unroll
        for (int nt = 0; nt < 4; ++nt)
          acc[g][nt] = __builtin_amdgcn_mfma_f32_16x16x32_f16(afr, bfr[nt], acc[g][nt], 0, 0, 0);
      }
    }
  };

  if (!leaf) {
    // chunk 0: pre-summed child h (k 0..255) — pure f16 copy
    const _Float16* hp = hsum_in + (long)(m0 + sr) * HD;
#pragma unroll
    for (int gi = 0; gi < 8; ++gi) {
      int g8 = s4 * 8 + gi;
      *(half8*)(&As[sr][((g8 ^ (sr & 7)) * 8)]) = *(const half8*)(hp + g8 * 8);
    }
    __syncthreads();
    gemm_chunk(0);
    __syncthreads();
  }

  // chunk 1: embed pair-sum (k 256..511 of W)
  {
    const int sm = m0 + sr;
    const int sb = sm >> l;
    const int sj = sm & (cnt - 1);
    const float* e0 = embed + ((long)sb * 1023 + csoff + 2 * sj) * 256;
    const float* e1 = e0 + 256;
#pragma unroll
    for (int gi = 0; gi < 8; ++gi) {
      int g8 = s4 * 8 + gi;
      floatx4 x0 = *(const floatx4*)(e0 + g8 * 8);
      floatx4 x1 = *(const floatx4*)(e0 + g8 * 8 + 4);
      floatx4 y0 = *(const floatx4*)(e1 + g8 * 8);
      floatx4 y1 = *(const floatx4*)(e1 + g8 * 8 + 4);
      half8 s;
#pragma unroll
      for (int e = 0; e < 4; ++e) { s[e] = (_Float16)(x0[e] + y0[e]); s[4 + e] = (_Float16)(x1[e] + y1[e]); }
      *(half8*)(&As[sr][((g8 ^ (sr & 7)) * 8)]) = s;
    }
  }
  __syncthreads();
  gemm_chunk(256);

  // ---------------- epilogue: all in-lane, no barriers ----------------
  // lane cell: data row = m0 + wave*16 + quad*4 + e; weight col = n0 + nt*16 + lm
  const int gmb = m0 + wave * 16 + quad * 4;
#pragma unroll
  for (int nt = 0; nt < 4; ++nt) {
    const int coln = n0 + nt * 16 + lm;
    const float b0 = bias[coln];
    const float b1 = bias[HD + coln];
    const float b2 = bias[2 * HD + coln];
    const float b3 = bias[3 * HD + coln];
    const float clv = leaf ? csum_in[coln] : 0.f;
    float hv[4], cvv[4];
#pragma unroll
    for (int e = 0; e < 4; ++e) {
      float cs = leaf ? clv : csum_in[(long)(gmb + e) * HD + coln];
      float zf = acc[0][nt][e] + b0;
      float zi = acc[1][nt][e] + b1;
      float zu = acc[2][nt][e] + b2;
      float zo = acc[3][nt][e] + b3;
      float f = sigmf_(zf), ig = sigmf_(zi), uu = tanhf_(zu), oo = sigmf_(zo);
      float cn = ig * uu + f * cs;
      cvv[e] = cn;
      hv[e] = oo * tanhf_(cn);
    }
    const long pr = (long)(gmb >> 1);
    hsum_out[pr * HD + coln] = (_Float16)(hv[0] + hv[1]);
    hsum_out[(pr + 1) * HD + coln] = (_Float16)(hv[2] + hv[3]);
    csum_out[pr * HD + coln] = cvv[0] + cvv[1];
    csum_out[(pr + 1) * HD + coln] = cvv[2] + cvv[3];
  }
}

// ---------------------------------------------------------------------------
// fused tail: levels 4..0 + MLP head. One block per batch (128 blocks, 512thr).
// Tree recursion entirely in LDS (h pair-sums f16 swizzled, c pair-sums f32).
// Wave w covers all 4 gates x 32 cols (2 col-tiles) of its 16-row (max) slab.
// ---------------------------------------------------------------------------
__global__ __launch_bounds__(512, 2)
void tail_kernel(const _Float16* __restrict__ Hs_in, const float* __restrict__ Cs_in,
                 const float* __restrict__ embed, const _Float16* __restrict__ Wh,
                 const float* __restrict__ bsum,
                 const float* __restrict__ W1, const float* __restrict__ bl1,
                 const float* __restrict__ W2, const float* __restrict__ bl2,
                 const float* __restrict__ W3, const float* __restrict__ bl3,
                 const float* __restrict__ W4, const float* __restrict__ bl4,
                 float* __restrict__ out)
{
  __shared__ _Float16 HS[16][256];   // h pair-sums, A-layout (swizzled granules)
  __shared__ _Float16 ES[16][256];   // embed pair-sums, A-layout
  __shared__ float CS[16][256];      // c pair-sums (linear)
  __shared__ float ha[HD], hb1[HD], hb2[HD];

  const int b = blockIdx.x;
  const int t = threadIdx.x;
  const int wave = t >> 6;
  const int lane = t & 63;
  const int lm = lane & 15;
  const int quad = lane >> 4;
  const int w32 = wave * 32;

  // init HS/CS from the l=5 standalone outputs (16 rows per batch)
  {
    const int row = t >> 5, g8 = t & 31;
    *(half8*)(&HS[row][((g8 ^ (row & 7)) * 8)]) =
        *(const half8*)(Hs_in + (long)(b * 16 + row) * HD + g8 * 8);
    const int c8 = (t & 31) * 8;
    *(floatx4*)(&CS[row][c8])     = *(const floatx4*)(Cs_in + (long)(b * 16 + row) * HD + c8);
    *(floatx4*)(&CS[row][c8 + 4]) = *(const floatx4*)(Cs_in + (long)(b * 16 + row) * HD + c8 + 4);
  }
  __syncthreads();

  for (int l = 4; l >= 0; --l) {
    const int rows = 1 << l;
    const int csoff = (2 << l) - 1;
    // stage embed pair-sums for active rows
    {
      const int row = t >> 5, g8 = t & 31;
      if (row < rows) {
        const float* e0 = embed + ((long)b * 1023 + csoff + 2 * row) * 256;
        const float* e1 = e0 + 256;
        floatx4 x0 = *(const floatx4*)(e0 + g8 * 8);
        floatx4 x1 = *(const floatx4*)(e0 + g8 * 8 + 4);
        floatx4 y0 = *(const floatx4*)(e1 + g8 * 8);
        floatx4 y1 = *(const floatx4*)(e1 + g8 * 8 + 4);
        half8 s;
#pragma unroll
        for (int e = 0; e < 4; ++e) { s[e] = (_Float16)(x0[e] + y0[e]); s[4 + e] = (_Float16)(x1[e] + y1[e]); }
        *(half8*)(&ES[row][((g8 ^ (row & 7)) * 8)]) = s;
      }
    }
    __syncthreads();

    // GEMM: K=512 (h half from HS, embed half from ES), rows padded to 16
    floatx4 acc[4][2] = {};
    const int asw = lm & 7;
#pragma unroll
    for (int ks = 0; ks < 16; ++ks) {
      const _Float16* sp = (ks < 8) ? &HS[lm][0] : &ES[lm][0];
      half8 afr = *(const half8*)(sp + ((((ks & 7) * 4 + quad) ^ asw) * 8));
#pragma unroll
      for (int g = 0; g < 4; ++g) {
#pragma unroll
        for (int tc = 0; tc < 2; ++tc) {
          half8 bfr = *(const half8*)(Wh + (long)(g * HD + w32 + tc * 16 + lm) * KD
                                      + ks * 32 + quad * 8);
          acc[g][tc] = __builtin_amdgcn_mfma_f32_16x16x32_f16(afr, bfr, acc[g][tc], 0, 0, 0);
        }
      }
    }

    // epilogue: compute cells (reads CS), then barrier, then write HS/CS
    float hv[2][4], cvv[2][4];
#pragma unroll
    for (int tc = 0; tc < 2; ++tc) {
      const int coln = w32 + tc * 16 + lm;
      const float b0 = bsum[coln];
      const float b1 = bsum[HD + coln];
      const float b2 = bsum[2 * HD + coln];
      const float b3 = bsum[3 * HD + coln];
#pragma unroll
      for (int e = 0; e < 4; ++e) {
        const int r = quad * 4 + e;
        float cs = (r < rows) ? CS[r][coln] : 0.f;
        float zf = acc[0][tc][e] + b0;
        float zi = acc[1][tc][e] + b1;
        float zu = acc[2][tc][e] + b2;
        float zo = acc[3][tc][e] + b3;
        float f = sigmf_(zf), ig = sigmf_(zi), uu = tanhf_(zu), oo = sigmf_(zo);
        float cn = ig * uu + f * cs;
        cvv[tc][e] = cn;
        hv[tc][e] = oo * tanhf_(cn);
      }
    }
    __syncthreads();   // all CS/HS reads complete before overwrite

    if (l > 0) {
#pragma unroll
      for (int tc = 0; tc < 2; ++tc) {
        const int coln = w32 + tc * 16 + lm;
#pragma unroll
        for (int ep = 0; ep < 2; ++ep) {
          const int r0 = quad * 4 + 2 * ep;
          if (r0 < rows) {
            const int pr = (r0 >> 1);
            HS[pr][((coln >> 3) ^ (pr & 7)) * 8 + (coln & 7)] =
                (_Float16)(hv[tc][2 * ep] + hv[tc][2 * ep + 1]);
            CS[pr][coln] = cvv[tc][2 * ep] + cvv[tc][2 * ep + 1];
          }
        }
      }
    } else if (quad == 0) {
#pragma unroll
      for (int tc = 0; tc < 2; ++tc)
        ha[w32 + tc * 16 + lm] = hv[tc][0];   // root h (row 0), f32
    }
    __syncthreads();
  }

  // ---------------- MLP head (first 256 threads) ----------------
  const int n = t;
  if (t < 256) {
    const float* w1 = W1 + (long)n * HD;
    const float* w2 = W2 + (long)n * HD;
    float s1 = bl1[n], s2 = bl2[n];
    for (int k = 0; k < HD; k += 4) {
      floatx4 av = *(const floatx4*)(&ha[k]);
      floatx4 w1v = *(const floatx4*)(w1 + k);
      floatx4 w2v = *(const floatx4*)(w2 + k);
#pragma unroll
      for (int e = 0; e < 4; ++e) { s1 += av[e] * w1v[e]; s2 += av[e] * w2v[e]; }
    }
    hb1[n] = tanhf_(s1);
    hb2[n] = fmaxf(s2, 0.f);
  }
  __syncthreads();
  float s3 = 0.f;
  if (t < 256) {
    const float* w3 = W3 + (long)n * HD;
    s3 = bl3[n];
    for (int k = 0; k < HD; k += 4) {
      floatx4 av = *(const floatx4*)(&hb2[k]);
      floatx4 wv = *(const floatx4*)(w3 + k);
#pragma unroll
      for (int e = 0; e < 4; ++e) s3 += av[e] * wv[e];
    }
  }
  __syncthreads();
  if (t < 256) ha[n] = hb1[n] + s3;
  __syncthreads();
  if (t < 256) {
    const float* w4 = W4 + (long)n * HD;
    float s4 = bl4[n];
    for (int k = 0; k < HD; k += 4) {
      floatx4 av = *(const floatx4*)(&ha[k]);
      floatx4 wv = *(const floatx4*)(w4 + k);
#pragma unroll
      for (int e = 0; e < 4; ++e) s4 += av[e] * wv[e];
    }
    out[(long)b * HD + n] = fmaxf(s4, 0.f);
  }
}

// ---------------------------------------------------------------------------
extern "C" void kernel_launch(void* const* d_in, const int* in_sizes, int n_in,
                              void* d_out, int out_size, void* d_ws, size_t ws_size,
                              hipStream_t stream)
{
  (void)in_sizes; (void)n_in; (void)out_size; (void)ws_size;
  const float* embed = (const float*)d_in[0];
  const float* Wf  = (const float*)d_in[1];
  const float* bf_ = (const float*)d_in[2];
  const float* b_f = (const float*)d_in[3];
  const float* Wi  = (const float*)d_in[4];
  const float* bi_ = (const float*)d_in[5];
  const float* b_i = (const float*)d_in[6];
  const float* Wu  = (const float*)d_in[7];
  const float* bu_ = (const float*)d_in[8];
  const float* b_u = (const float*)d_in[9];
  const float* Wo  = (const float*)d_in[10];
  const float* bo_ = (const float*)d_in[11];
  const float* b_o = (const float*)d_in[12];
  const float* W1  = (const float*)d_in[13];
  const float* bl1 = (const float*)d_in[14];
  const float* W2  = (const float*)d_in[15];
  const float* bl2 = (const float*)d_in[16];
  const float* W3  = (const float*)d_in[17];
  const float* bl3 = (const float*)d_in[18];
  const float* W4  = (const float*)d_in[19];
  const float* bl4 = (const float*)d_in[20];

  char* ws = (char*)d_ws;
  _Float16* Wh   = (_Float16*)(ws);                 // 1,048,576 B
  float* bsum    = (float*)(ws + 1048576);          // 4 KB
  float* bias2   = (float*)(ws + 1052672);          // 4 KB
  float* cleaf2  = (float*)(ws + 1056768);          // 1 KB
  _Float16* HsA  = (_Float16*)(ws + 1516544);       // 8,388,608 B  (max 16384x256 f16)
  float* CsA     = (float*)(ws + 9905152);          // 16,777,216 B (max 16384x256 f32)
  _Float16* HsB  = (_Float16*)(ws + 26682368);      // 8,388,608 B
  float* CsB     = (float*)(ws + 35070976);         // 16,777,216 B -> end 51,848,192 B

  prep_kernel<<<dim3(16), dim3(256), 0, stream>>>(bf_, b_f, bi_, b_i, bu_, b_u, bo_, b_o,
                                                  Wf, Wi, Wu, Wo, bsum, bias2, cleaf2);
  wcvt_kernel<<<dim3(512), dim3(256), 0, stream>>>(Wf, Wi, Wu, Wo, Wh);

  _Float16* hbufs[2] = {HsA, HsB};
  float* cbufs[2] = {CsA, CsB};
  int pp = 0;
  const _Float16* hin = nullptr;
  const float* cin = cleaf2;
  for (int l = 8; l >= 5; --l) {
    const int leaf = (l == 8);
    dim3 grid(1 << l, 4);
    level_kernel<<<grid, dim3(512), 0, stream>>>(hin, cin, embed, Wh,
                                                 leaf ? bias2 : bsum,
                                                 hbufs[pp], cbufs[pp], l, leaf);
    hin = hbufs[pp];
    cin = cbufs[pp];
    pp ^= 1;
  }
  // after l=5, hin/cin point at the 16-rows-per-batch pair-sums
  tail_kernel<<<dim3(128), dim3(512), 0, stream>>>(hin, cin, embed, Wh, bsum,
                                                   W1, bl1, W2, bl2, W3, bl3, W4, bl4,
                                                   (float*)d_out);
}

// Round 6
// 762.388 us; speedup vs baseline: 1.2205x; 1.2205x over previous
//
#include <hip/hip_runtime.h>

#define HD 256
#define KD 512

typedef _Float16 half8 __attribute__((ext_vector_type(8)));
typedef _Float16 half2v __attribute__((ext_vector_type(2)));
typedef _Float16 half4v __attribute__((ext_vector_type(4)));
typedef float floatx4 __attribute__((ext_vector_type(4)));
typedef float floatx2 __attribute__((ext_vector_type(2)));

__device__ __forceinline__ float sigmf_(float x) { return 1.f / (1.f + __expf(-x)); }
__device__ __forceinline__ float tanhf_(float x) {
  x = fminf(fmaxf(x, -15.f), 15.f);
  float e = __expf(2.f * x);
  return (e - 1.f) / (e + 1.f);
}

// ---------------------------------------------------------------------------
// prep (parallel, 16 blocks): gate bias sums, leaf csum (=2*c_leaf), and
// leaf-level folded bias: bias2[g][n] = bsum[g][n] + W_g[n][0:256]·(2*h_leaf)
// block id = (gate g = bid>>2, col-quarter q = bid&3)
// ---------------------------------------------------------------------------
__global__ void prep_kernel(const float* __restrict__ bf_, const float* __restrict__ b_f,
                            const float* __restrict__ bi_, const float* __restrict__ b_i,
                            const float* __restrict__ bu_, const float* __restrict__ b_u,
                            const float* __restrict__ bo_, const float* __restrict__ b_o,
                            const float* __restrict__ Wf, const float* __restrict__ Wi,
                            const float* __restrict__ Wu, const float* __restrict__ Wo,
                            float* __restrict__ bsum, float* __restrict__ bias2,
                            float* __restrict__ cleaf2)
{
  __shared__ float hl2[HD];
  __shared__ float part[64][4];
  const int t = threadIdx.x;
  float sf = bf_[t] + b_f[t];
  float si = bi_[t] + b_i[t];
  float su = bu_[t] + b_u[t];
  float so = bo_[t] + b_o[t];
  float ig = 1.f / (1.f + expf(-si));
  float uu = tanhf(su);
  float cl = ig * uu;
  float hl = (1.f / (1.f + expf(-so))) * tanhf(cl);
  hl2[t] = 2.f * hl;
  if (blockIdx.x == 0) {
    bsum[t] = sf; bsum[HD + t] = si; bsum[2 * HD + t] = su; bsum[3 * HD + t] = so;
    cleaf2[t] = cl + cl;
  }
  __syncthreads();
  const int g = blockIdx.x >> 2, q = blockIdx.x & 3;
  const int nl = t >> 2, kq = t & 3;
  const float* Wg = (g == 0) ? Wf : (g == 1) ? Wi : (g == 2) ? Wu : Wo;
  const float* w = Wg + (long)(q * 64 + nl) * KD + kq * 64;
  float s = 0.f;
  for (int k = 0; k < 64; k += 4) {
    floatx4 wv = *(const floatx4*)(w + k);
    floatx4 hv = *(const floatx4*)(&hl2[kq * 64 + k]);
    s += wv[0] * hv[0] + wv[1] * hv[1] + wv[2] * hv[2] + wv[3] * hv[3];
  }
  part[nl][kq] = s;
  __syncthreads();
  if (kq == 0) {
    const int n = q * 64 + nl;
    float tot = part[nl][0] + part[nl][1] + part[nl][2] + part[nl][3];
    float bg = (g == 0) ? (bf_[n] + b_f[n]) : (g == 1) ? (bi_[n] + b_i[n])
             : (g == 2) ? (bu_[n] + b_u[n]) : (bo_[n] + b_o[n]);
    bias2[g * HD + n] = bg + tot;
  }
}

// ---------------------------------------------------------------------------
// convert the 4 gate weights (fp32, [256][512]) to f16 packed [g][256][512]
// ---------------------------------------------------------------------------
__global__ void wcvt_kernel(const float* __restrict__ Wf, const float* __restrict__ Wi,
                            const float* __restrict__ Wu, const float* __restrict__ Wo,
                            _Float16* __restrict__ Wh)
{
  int idx = (blockIdx.x * 256 + threadIdx.x) * 4;
  int g = idx >> 17;
  int rem = idx & ((1 << 17) - 1);
  const float* src = (g == 0) ? Wf : (g == 1) ? Wi : (g == 2) ? Wu : Wo;
  floatx4 v = *(const floatx4*)(src + rem);
  half4v o;
  o[0] = (_Float16)v[0]; o[1] = (_Float16)v[1]; o[2] = (_Float16)v[2]; o[3] = (_Float16)v[3];
  *(half4v*)(Wh + idx) = o;
}

// ---------------------------------------------------------------------------
// fused level kernel (round-4 structure, 256-thr blocks for occupancy).
// block = 256 thr = 4 waves; wave = gate. Tile: 64 rows x 64 cols per gate.
// grid = (M/64, 4); n0 = blockIdx.y*64; M = 128*2^l rows (pairs at level l).
// Interfaces PRE-PAIR-SUMMED: hsum_in[m]=h[2m]+h[2m+1] (f16),
// csum_in[m]=c[2m]+c[2m+1] (f32); outputs the same at parent granularity.
// leaf: h-chunk folded into bias2 (K=256, embeds only); csum_in = cleaf2.
// fin : write per-root h rows (no pair-sum) to hsum_out.
// Proven-by-counters rules: (1) acc[][] only static indices (else scratch
// spill: R1-3's 1GB WRITE_SIZE); (2) wave=gate + depth-1 B prefetch beats
// wave=all-gates (R5's 16 unprefetched B-loads/ks regressed 2x).
// ---------------------------------------------------------------------------
__global__ __launch_bounds__(256)
void level_kernel(const _Float16* __restrict__ hsum_in,
                  const float* __restrict__ csum_in,
                  const float* __restrict__ embed,
                  const _Float16* __restrict__ Wh,
                  const float* __restrict__ bias,
                  _Float16* __restrict__ hsum_out,
                  float* __restrict__ csum_out,
                  int l, int leaf, int fin)
{
  __shared__ __attribute__((aligned(16))) char smraw[64 * 256 * 2];  // 32 KB
  auto As = (_Float16(*)[256])smraw;    // 64 rows x 256 f16, XOR-swizzled granules
  auto Zs = (float(*)[16][66])smraw;    // [4 gates][16 rows][66] padded, aliased

  const int cnt = 1 << l;
  const int csoff = (2 << l) - 1;
  const int m0 = blockIdx.x * 64;
  const int n0 = blockIdx.y * 64;
  const int t = threadIdx.x;
  const int g = t >> 6;                 // wave = gate
  const int lane = t & 63;
  const int lm = lane & 15;
  const int quad = lane >> 4;

  floatx4 acc[4][4] = {};               // [mt][nt]

  // staging mapping: row sr = t>>2 (0..63), k-quarter s4 = t&3
  const int sr = t >> 2;
  const int s4 = t & 3;
  const int sm = m0 + sr;
  const int sb = sm >> l;
  const int sj = sm & (cnt - 1);
  const long ebase = ((long)sb * 1023 + csoff + 2 * sj) * 256;

  const _Float16* wg = Wh + (long)(g * HD + n0) * KD;

  // K-loop with depth-1 B double-buffer: ks+1 weight loads fly under ks MFMAs.
  auto gemm_chunk = [&](int kbase) {
    const _Float16* wb = wg + kbase + quad * 8;
    half8 bcur[4], bnxt[4];
#pragma unroll
    for (int nt = 0; nt < 4; ++nt)
      bcur[nt] = *(const half8*)(wb + (long)(nt * 16 + lm) * KD);
#pragma unroll
    for (int ks = 0; ks < 8; ++ks) {
      if (ks < 7) {
#pragma unroll
        for (int nt = 0; nt < 4; ++nt)
          bnxt[nt] = *(const half8*)(wb + (long)(nt * 16 + lm) * KD + (ks + 1) * 32);
      }
      half8 afr[4];
#pragma unroll
      for (int mt = 0; mt < 4; ++mt) {
        int row = mt * 16 + lm;
        afr[mt] = *(const half8*)(&As[row][(((ks * 4 + quad) ^ (row & 7)) * 8)]);
      }
#pragma unroll
      for (int mt = 0; mt < 4; ++mt)
#pragma unroll
        for (int nt = 0; nt < 4; ++nt)
          acc[mt][nt] = __builtin_amdgcn_mfma_f32_16x16x32_f16(afr[mt], bcur[nt], acc[mt][nt], 0, 0, 0);
#pragma unroll
      for (int nt = 0; nt < 4; ++nt) bcur[nt] = bnxt[nt];
    }
  };

  if (!leaf) {
    // chunk 0: pre-summed child h (k 0..255) — pure f16 copy
    const _Float16* hp = hsum_in + (long)sm * HD;
#pragma unroll
    for (int gi = 0; gi < 8; ++gi) {
      int g8 = s4 * 8 + gi;
      *(half8*)(&As[sr][((g8 ^ (sr & 7)) * 8)]) = *(const half8*)(hp + g8 * 8);
    }
    __syncthreads();
    gemm_chunk(0);
    __syncthreads();
  }

  // chunk 1: embed pair-sum (k 256..511 of W) — nt loads: streamed once
  {
    const float* e0 = embed + ebase;
    const float* e1 = e0 + 256;
#pragma unroll
    for (int gi = 0; gi < 8; ++gi) {
      int g8 = s4 * 8 + gi;
      floatx4 x0 = __builtin_nontemporal_load((const floatx4*)(e0 + g8 * 8));
      floatx4 x1 = __builtin_nontemporal_load((const floatx4*)(e0 + g8 * 8 + 4));
      floatx4 y0 = __builtin_nontemporal_load((const floatx4*)(e1 + g8 * 8));
      floatx4 y1 = __builtin_nontemporal_load((const floatx4*)(e1 + g8 * 8 + 4));
      half8 s;
#pragma unroll
      for (int e = 0; e < 4; ++e) { s[e] = (_Float16)(x0[e] + y0[e]); s[4 + e] = (_Float16)(x1[e] + y1[e]); }
      *(half8*)(&As[sr][((g8 ^ (sr & 7)) * 8)]) = s;
    }
  }
  __syncthreads();
  gemm_chunk(256);

  // ---------------- epilogue: 4 fully-unrolled 16-row slabs ----------------
  // write: wave g dumps its 16x64 z-slab into Zs[g] (quad stride 264 -> banks
  // +8, only 2-way aliasing = free). read: thread = (row-pair rp, col-pair cl).
  const int rp = t >> 5;                // 0..7
  const int cl = t & 31;                // 0..31
  const int c0 = cl * 2;
  const int coln = n0 + c0;
  floatx2 bb[4];
#pragma unroll
  for (int g2 = 0; g2 < 4; ++g2) bb[g2] = *(const floatx2*)(bias + g2 * HD + coln);
  floatx2 clv = {0.f, 0.f};
  if (leaf) clv = *(const floatx2*)(csum_in + coln);

#pragma unroll
  for (int mt = 0; mt < 4; ++mt) {
    __syncthreads();                    // As/Zs reads of previous phase done
#pragma unroll
    for (int nt = 0; nt < 4; ++nt)
#pragma unroll
      for (int e = 0; e < 4; ++e)
        Zs[g][quad * 4 + e][nt * 16 + lm] = acc[mt][nt][e];
    __syncthreads();

    const int mmA = m0 + mt * 16 + 2 * rp;
    floatx2 csA, csB;
    if (leaf) { csA = clv; csB = clv; }
    else {
      csA = *(const floatx2*)(csum_in + (long)mmA * HD + coln);
      csB = *(const floatx2*)(csum_in + (long)(mmA + 1) * HD + coln);
    }
    float hs[2][2], cv[2][2];
#pragma unroll
    for (int rr = 0; rr < 2; ++rr)
#pragma unroll
      for (int cc = 0; cc < 2; ++cc) {
        float zf = Zs[0][2 * rp + rr][c0 + cc] + bb[0][cc];
        float zi = Zs[1][2 * rp + rr][c0 + cc] + bb[1][cc];
        float zu = Zs[2][2 * rp + rr][c0 + cc] + bb[2][cc];
        float zo = Zs[3][2 * rp + rr][c0 + cc] + bb[3][cc];
        float csv = rr ? csB[cc] : csA[cc];
        float f = sigmf_(zf), ig = sigmf_(zi), uu = tanhf_(zu), oo = sigmf_(zo);
        float cn = ig * uu + f * csv;
        cv[rr][cc] = cn;
        hs[rr][cc] = oo * tanhf_(cn);
      }
    if (fin) {
      half2v hv0; hv0[0] = (_Float16)hs[0][0]; hv0[1] = (_Float16)hs[0][1];
      half2v hv1; hv1[0] = (_Float16)hs[1][0]; hv1[1] = (_Float16)hs[1][1];
      *(half2v*)(hsum_out + (long)mmA * HD + coln) = hv0;
      *(half2v*)(hsum_out + (long)(mmA + 1) * HD + coln) = hv1;
    } else {
      const long pr = mmA >> 1;
      half2v hv; hv[0] = (_Float16)(hs[0][0] + hs[1][0]); hv[1] = (_Float16)(hs[0][1] + hs[1][1]);
      floatx2 cvv; cvv[0] = cv[0][0] + cv[1][0]; cvv[1] = cv[0][1] + cv[1][1];
      *(half2v*)(hsum_out + pr * HD + coln) = hv;
      *(floatx2*)(csum_out + pr * HD + coln) = cvv;
    }
  }
}

// ---------------------------------------------------------------------------
// fused head: y=tanh(hr@W1+b1); y2=relu(hr@W2+b2)@W3+b3; out=relu((y+y2)@W4+b4)
// one block per batch row, all stages through LDS
// ---------------------------------------------------------------------------
__global__ void head_all_kernel(const _Float16* __restrict__ hr,
                                const float* __restrict__ W1, const float* __restrict__ bl1,
                                const float* __restrict__ W2, const float* __restrict__ bl2,
                                const float* __restrict__ W3, const float* __restrict__ bl3,
                                const float* __restrict__ W4, const float* __restrict__ bl4,
                                float* __restrict__ out)
{
  __shared__ float a[HD];
  __shared__ float t1s[HD];
  __shared__ float t2s[HD];
  int b = blockIdx.x, n = threadIdx.x;
  a[n] = (float)hr[b * HD + n];
  __syncthreads();
  {
    const float* w1 = W1 + n * HD;
    const float* w2 = W2 + n * HD;
    float s1 = bl1[n], s2 = bl2[n];
    for (int k = 0; k < HD; k += 4) {
      floatx4 av = *(const floatx4*)(&a[k]);
      floatx4 w1v = *(const floatx4*)(w1 + k);
      floatx4 w2v = *(const floatx4*)(w2 + k);
#pragma unroll
      for (int e = 0; e < 4; ++e) { s1 += av[e] * w1v[e]; s2 += av[e] * w2v[e]; }
    }
    t1s[n] = tanhf_(s1);
    t2s[n] = fmaxf(s2, 0.f);
  }
  __syncthreads();
  {
    const float* w3 = W3 + n * HD;
    float s3 = bl3[n];
    for (int k = 0; k < HD; k += 4) {
      floatx4 av = *(const floatx4*)(&t2s[k]);
      floatx4 wv = *(const floatx4*)(w3 + k);
#pragma unroll
      for (int e = 0; e < 4; ++e) s3 += av[e] * wv[e];
    }
    __syncthreads();
    a[n] = t1s[n] + s3;
  }
  __syncthreads();
  {
    const float* w4 = W4 + n * HD;
    float s4 = bl4[n];
    for (int k = 0; k < HD; k += 4) {
      floatx4 av = *(const floatx4*)(&a[k]);
      floatx4 wv = *(const floatx4*)(w4 + k);
#pragma unroll
      for (int e = 0; e < 4; ++e) s4 += av[e] * wv[e];
    }
    out[b * HD + n] = fmaxf(s4, 0.f);
  }
}

// ---------------------------------------------------------------------------
extern "C" void kernel_launch(void* const* d_in, const int* in_sizes, int n_in,
                              void* d_out, int out_size, void* d_ws, size_t ws_size,
                              hipStream_t stream)
{
  (void)in_sizes; (void)n_in; (void)out_size; (void)ws_size;
  const float* embed = (const float*)d_in[0];
  const float* Wf  = (const float*)d_in[1];
  const float* bf_ = (const float*)d_in[2];
  const float* b_f = (const float*)d_in[3];
  const float* Wi  = (const float*)d_in[4];
  const float* bi_ = (const float*)d_in[5];
  const float* b_i = (const float*)d_in[6];
  const float* Wu  = (const float*)d_in[7];
  const float* bu_ = (const float*)d_in[8];
  const float* b_u = (const float*)d_in[9];
  const float* Wo  = (const float*)d_in[10];
  const float* bo_ = (const float*)d_in[11];
  const float* b_o = (const float*)d_in[12];
  const float* W1  = (const float*)d_in[13];
  const float* bl1 = (const float*)d_in[14];
  const float* W2  = (const float*)d_in[15];
  const float* bl2 = (const float*)d_in[16];
  const float* W3  = (const float*)d_in[17];
  const float* bl3 = (const float*)d_in[18];
  const float* W4  = (const float*)d_in[19];
  const float* bl4 = (const float*)d_in[20];

  char* ws = (char*)d_ws;
  _Float16* Wh   = (_Float16*)(ws);                 // 1,048,576 B
  float* bsum    = (float*)(ws + 1048576);          // 4 KB
  float* bias2   = (float*)(ws + 1052672);          // 4 KB
  float* cleaf2  = (float*)(ws + 1056768);          // 1 KB
  _Float16* hr   = (_Float16*)(ws + 1057792);       // 64 KB  (root h, f16)
  _Float16* HsA  = (_Float16*)(ws + 1516544);       // 8,388,608 B
  float* CsA     = (float*)(ws + 9905152);          // 16,777,216 B
  _Float16* HsB  = (_Float16*)(ws + 26682368);      // 8,388,608 B
  float* CsB     = (float*)(ws + 35070976);         // 16,777,216 B -> end 51,848,192 B

  prep_kernel<<<dim3(16), dim3(256), 0, stream>>>(bf_, b_f, bi_, b_i, bu_, b_u, bo_, b_o,
                                                  Wf, Wi, Wu, Wo, bsum, bias2, cleaf2);
  wcvt_kernel<<<dim3(512), dim3(256), 0, stream>>>(Wf, Wi, Wu, Wo, Wh);

  _Float16* hbufs[2] = {HsA, HsB};
  float* cbufs[2] = {CsA, CsB};
  int pp = 0;
  const _Float16* hin = nullptr;
  const float* cin = cleaf2;
  for (int l = 8; l >= 0; --l) {
    const int leaf = (l == 8);
    const int fin = (l == 0);
    _Float16* hout = fin ? hr : hbufs[pp];
    float* cout = cbufs[pp];
    dim3 grid(2 << l, 4);
    level_kernel<<<grid, dim3(256), 0, stream>>>(hin, cin, embed, Wh,
                                                 leaf ? bias2 : bsum,
                                                 hout, cout, l, leaf, fin);
    hin = hbufs[pp];
    cin = cbufs[pp];
    pp ^= 1;
  }

  head_all_kernel<<<dim3(128), dim3(256), 0, stream>>>(hr, W1, bl1, W2, bl2, W3, bl3,
                                                       W4, bl4, (float*)d_out);
}

// Round 7
// 509.524 us; speedup vs baseline: 1.8262x; 1.4963x over previous
//
#include <hip/hip_runtime.h>

#define HD 256
#define KD 512

typedef _Float16 half8 __attribute__((ext_vector_type(8)));
typedef _Float16 half2v __attribute__((ext_vector_type(2)));
typedef _Float16 half4v __attribute__((ext_vector_type(4)));
typedef float floatx4 __attribute__((ext_vector_type(4)));
typedef float floatx2 __attribute__((ext_vector_type(2)));

__device__ __forceinline__ float sigmf_(float x) { return 1.f / (1.f + __expf(-x)); }
__device__ __forceinline__ float tanhf_(float x) {
  x = fminf(fmaxf(x, -15.f), 15.f);
  float e = __expf(2.f * x);
  return (e - 1.f) / (e + 1.f);
}

// ---------------------------------------------------------------------------
// prep (parallel, 16 blocks): gate bias sums, leaf csum (=2*c_leaf), and
// leaf-level folded bias: bias2[g][n] = bsum[g][n] + W_g[n][0:256]·(2*h_leaf)
// ---------------------------------------------------------------------------
__global__ void prep_kernel(const float* __restrict__ bf_, const float* __restrict__ b_f,
                            const float* __restrict__ bi_, const float* __restrict__ b_i,
                            const float* __restrict__ bu_, const float* __restrict__ b_u,
                            const float* __restrict__ bo_, const float* __restrict__ b_o,
                            const float* __restrict__ Wf, const float* __restrict__ Wi,
                            const float* __restrict__ Wu, const float* __restrict__ Wo,
                            float* __restrict__ bsum, float* __restrict__ bias2,
                            float* __restrict__ cleaf2)
{
  __shared__ float hl2[HD];
  __shared__ float part[64][4];
  const int t = threadIdx.x;
  float sf = bf_[t] + b_f[t];
  float si = bi_[t] + b_i[t];
  float su = bu_[t] + b_u[t];
  float so = bo_[t] + b_o[t];
  float ig = 1.f / (1.f + expf(-si));
  float uu = tanhf(su);
  float cl = ig * uu;
  float hl = (1.f / (1.f + expf(-so))) * tanhf(cl);
  hl2[t] = 2.f * hl;
  if (blockIdx.x == 0) {
    bsum[t] = sf; bsum[HD + t] = si; bsum[2 * HD + t] = su; bsum[3 * HD + t] = so;
    cleaf2[t] = cl + cl;
  }
  __syncthreads();
  const int g = blockIdx.x >> 2, q = blockIdx.x & 3;
  const int nl = t >> 2, kq = t & 3;
  const float* Wg = (g == 0) ? Wf : (g == 1) ? Wi : (g == 2) ? Wu : Wo;
  const float* w = Wg + (long)(q * 64 + nl) * KD + kq * 64;
  float s = 0.f;
  for (int k = 0; k < 64; k += 4) {
    floatx4 wv = *(const floatx4*)(w + k);
    floatx4 hv = *(const floatx4*)(&hl2[kq * 64 + k]);
    s += wv[0] * hv[0] + wv[1] * hv[1] + wv[2] * hv[2] + wv[3] * hv[3];
  }
  part[nl][kq] = s;
  __syncthreads();
  if (kq == 0) {
    const int n = q * 64 + nl;
    float tot = part[nl][0] + part[nl][1] + part[nl][2] + part[nl][3];
    float bg = (g == 0) ? (bf_[n] + b_f[n]) : (g == 1) ? (bi_[n] + b_i[n])
             : (g == 2) ? (bu_[n] + b_u[n]) : (bo_[n] + b_o[n]);
    bias2[g * HD + n] = bg + tot;
  }
}

// ---------------------------------------------------------------------------
// convert the 4 gate weights (fp32, [256][512]) to f16 packed [g][256][512]
// ---------------------------------------------------------------------------
__global__ void wcvt_kernel(const float* __restrict__ Wf, const float* __restrict__ Wi,
                            const float* __restrict__ Wu, const float* __restrict__ Wo,
                            _Float16* __restrict__ Wh)
{
  int idx = (blockIdx.x * 256 + threadIdx.x) * 4;
  int g = idx >> 17;
  int rem = idx & ((1 << 17) - 1);
  const float* src = (g == 0) ? Wf : (g == 1) ? Wi : (g == 2) ? Wu : Wo;
  floatx4 v = *(const floatx4*)(src + rem);
  half4v o;
  o[0] = (_Float16)v[0]; o[1] = (_Float16)v[1]; o[2] = (_Float16)v[2]; o[3] = (_Float16)v[3];
  *(half4v*)(Wh + idx) = o;
}

// ---------------------------------------------------------------------------
// esum: pre-materialized f16 embed pair-sums, parent-indexed.
// esum[b][p][c] = embed[b][2p+1][c] + embed[b][2p+2][c], p in [0,511).
// Level l uses parents p = (2^l - 1) .. (2^(l+1) - 2) — a contiguous slice.
// grid (64, 128): task = bx*256+t over 511 rows x 32 granules per batch.
// ---------------------------------------------------------------------------
__global__ void esum_kernel(const float* __restrict__ embed, _Float16* __restrict__ esum)
{
  const int task = blockIdx.x * 256 + threadIdx.x;
  if (task >= 511 * 32) return;
  const int b = blockIdx.y;
  const int p = task >> 5, g8 = task & 31;
  const float* e0 = embed + ((long)b * 1023 + 2 * p + 1) * 256 + g8 * 8;
  const float* e1 = e0 + 256;
  floatx4 x0 = *(const floatx4*)(e0);
  floatx4 x1 = *(const floatx4*)(e0 + 4);
  floatx4 y0 = *(const floatx4*)(e1);
  floatx4 y1 = *(const floatx4*)(e1 + 4);
  half8 s;
#pragma unroll
  for (int e = 0; e < 4; ++e) { s[e] = (_Float16)(x0[e] + y0[e]); s[4 + e] = (_Float16)(x1[e] + y1[e]); }
  *(half8*)(esum + ((long)b * 511 + p) * 256 + g8 * 8) = s;
}

// ---------------------------------------------------------------------------
// level kernel (retiled for arithmetic intensity).
// block = 256 thr = 4 waves = (row-half rh) x (col-half ch).
// Block tile: 128 rows x 32 cols x ALL 4 gates; wave: 64 rows x 16 cols x 4g,
// acc[mt 4][gate 4] (static indices only!). grid = (8, M/128), x = col-block
// (fastest-varying -> same-A blocks dispatch-adjacent for cache reuse).
// B traffic: 128 KB/block (vs 512 KB at R4's 64-row tile). Epilogue fully
// in-lane (all 4 gates per cell in-register): no LDS exchange, no barriers.
// A inputs all f16: hsum (pair-summed h) and esum (pre-materialized).
// Proven rules: static acc indexing (R1-3 scratch spill); depth-1 B prefetch
// (R5 regression without it).
// ---------------------------------------------------------------------------
__global__ __launch_bounds__(256, 2)
void level_kernel(const _Float16* __restrict__ hsum_in,
                  const float* __restrict__ csum_in,
                  const _Float16* __restrict__ esum,
                  const _Float16* __restrict__ Wh,
                  const float* __restrict__ bias,
                  _Float16* __restrict__ hsum_out,
                  float* __restrict__ csum_out,
                  int l, int leaf, int fin)
{
  __shared__ _Float16 As[128][256];      // 64 KB, XOR-swizzled 16B granules

  const int cb = blockIdx.x;             // 0..7 col-block
  const int m0 = blockIdx.y * 128;
  const int t = threadIdx.x;
  const int wave = t >> 6;
  const int lane = t & 63;
  const int lm = lane & 15;
  const int quad = lane >> 4;
  const int rh = wave >> 1;              // row half (64 rows)
  const int ch = wave & 1;               // col half (16 cols)
  const int ncol = cb * 32 + ch * 16 + lm;

  floatx4 acc[4][4] = {};                // [mt][gate]

  // staging map: 8 threads/row, lane granule-id distinct low-3 bits so the
  // XOR-swizzled LDS stores cover all 8 bank groups (conflict-free).
  const int srow0 = t >> 3;              // 0..31, +32 per pass
  const int sg = t & 7;                  // granule low bits

  const _Float16* wb = Wh + (long)ncol * KD + quad * 8;

  auto gemm_chunk = [&](int kbase) {
    half8 bcur[4], bnxt[4];
#pragma unroll
    for (int g = 0; g < 4; ++g)
      bcur[g] = *(const half8*)(wb + (long)g * HD * KD + kbase);
#pragma unroll
    for (int ks = 0; ks < 8; ++ks) {
      if (ks < 7) {
#pragma unroll
        for (int g = 0; g < 4; ++g)
          bnxt[g] = *(const half8*)(wb + (long)g * HD * KD + kbase + (ks + 1) * 32);
      }
      half8 afr[4];
#pragma unroll
      for (int mt = 0; mt < 4; ++mt) {
        int row = rh * 64 + mt * 16 + lm;
        afr[mt] = *(const half8*)(&As[row][(((ks * 4 + quad) ^ (row & 7)) * 8)]);
      }
#pragma unroll
      for (int mt = 0; mt < 4; ++mt)
#pragma unroll
        for (int g = 0; g < 4; ++g)
          acc[mt][g] = __builtin_amdgcn_mfma_f32_16x16x32_f16(afr[mt], bcur[g], acc[mt][g], 0, 0, 0);
#pragma unroll
      for (int g = 0; g < 4; ++g) bcur[g] = bnxt[g];
    }
  };

  const int msk = (1 << l) - 1;

  if (!leaf) {
    // chunk 0: pre-summed child h (k 0..255) — pure f16 copy
#pragma unroll
    for (int p = 0; p < 4; ++p) {
      const int r = srow0 + 32 * p;
      const _Float16* src = hsum_in + (long)(m0 + r) * HD;
#pragma unroll
      for (int q = 0; q < 4; ++q) {
        int g8 = sg + 8 * q;
        *(half8*)(&As[r][((g8 ^ (r & 7)) * 8)]) = *(const half8*)(src + g8 * 8);
      }
    }
    __syncthreads();
    gemm_chunk(0);
    __syncthreads();
  }

  // chunk 1: embed pair-sums from esum (k 256..511 of W) — pure f16 copy
  {
#pragma unroll
    for (int p = 0; p < 4; ++p) {
      const int r = srow0 + 32 * p;
      const int sm = m0 + r;
      const long erow = (long)(sm >> l) * 511 + msk + (sm & msk);
      const _Float16* src = esum + erow * HD;
#pragma unroll
      for (int q = 0; q < 4; ++q) {
        int g8 = sg + 8 * q;
        *(half8*)(&As[r][((g8 ^ (r & 7)) * 8)]) = *(const half8*)(src + g8 * 8);
      }
    }
  }
  __syncthreads();
  gemm_chunk(256);

  // ---------------- epilogue: fully in-lane ----------------
  const float b0 = bias[ncol];
  const float b1 = bias[HD + ncol];
  const float b2 = bias[2 * HD + ncol];
  const float b3 = bias[3 * HD + ncol];
  const float clv = leaf ? csum_in[ncol] : 0.f;

#pragma unroll
  for (int mt = 0; mt < 4; ++mt) {
    const int mg0 = m0 + rh * 64 + mt * 16 + quad * 4;
    float hv[4], cvv[4];
#pragma unroll
    for (int e = 0; e < 4; ++e) {
      float cs = leaf ? clv : csum_in[(long)(mg0 + e) * HD + ncol];
      float zf = acc[mt][0][e] + b0;
      float zi = acc[mt][1][e] + b1;
      float zu = acc[mt][2][e] + b2;
      float zo = acc[mt][3][e] + b3;
      float f = sigmf_(zf), ig = sigmf_(zi), uu = tanhf_(zu), oo = sigmf_(zo);
      float cn = ig * uu + f * cs;
      cvv[e] = cn;
      hv[e] = oo * tanhf_(cn);
    }
    if (fin) {
#pragma unroll
      for (int e = 0; e < 4; ++e)
        hsum_out[(long)(mg0 + e) * HD + ncol] = (_Float16)hv[e];
    } else {
      const long pr = mg0 >> 1;
      hsum_out[pr * HD + ncol] = (_Float16)(hv[0] + hv[1]);
      hsum_out[(pr + 1) * HD + ncol] = (_Float16)(hv[2] + hv[3]);
      csum_out[pr * HD + ncol] = cvv[0] + cvv[1];
      csum_out[(pr + 1) * HD + ncol] = cvv[2] + cvv[3];
    }
  }
}

// ---------------------------------------------------------------------------
// fused head: y=tanh(hr@W1+b1); y2=relu(hr@W2+b2)@W3+b3; out=relu((y+y2)@W4+b4)
// ---------------------------------------------------------------------------
__global__ void head_all_kernel(const _Float16* __restrict__ hr,
                                const float* __restrict__ W1, const float* __restrict__ bl1,
                                const float* __restrict__ W2, const float* __restrict__ bl2,
                                const float* __restrict__ W3, const float* __restrict__ bl3,
                                const float* __restrict__ W4, const float* __restrict__ bl4,
                                float* __restrict__ out)
{
  __shared__ float a[HD];
  __shared__ float t1s[HD];
  __shared__ float t2s[HD];
  int b = blockIdx.x, n = threadIdx.x;
  a[n] = (float)hr[b * HD + n];
  __syncthreads();
  {
    const float* w1 = W1 + n * HD;
    const float* w2 = W2 + n * HD;
    float s1 = bl1[n], s2 = bl2[n];
    for (int k = 0; k < HD; k += 4) {
      floatx4 av = *(const floatx4*)(&a[k]);
      floatx4 w1v = *(const floatx4*)(w1 + k);
      floatx4 w2v = *(const floatx4*)(w2 + k);
#pragma unroll
      for (int e = 0; e < 4; ++e) { s1 += av[e] * w1v[e]; s2 += av[e] * w2v[e]; }
    }
    t1s[n] = tanhf_(s1);
    t2s[n] = fmaxf(s2, 0.f);
  }
  __syncthreads();
  {
    const float* w3 = W3 + n * HD;
    float s3 = bl3[n];
    for (int k = 0; k < HD; k += 4) {
      floatx4 av = *(const floatx4*)(&t2s[k]);
      floatx4 wv = *(const floatx4*)(w3 + k);
#pragma unroll
      for (int e = 0; e < 4; ++e) s3 += av[e] * wv[e];
    }
    __syncthreads();
    a[n] = t1s[n] + s3;
  }
  __syncthreads();
  {
    const float* w4 = W4 + n * HD;
    float s4 = bl4[n];
    for (int k = 0; k < HD; k += 4) {
      floatx4 av = *(const floatx4*)(&a[k]);
      floatx4 wv = *(const floatx4*)(w4 + k);
#pragma unroll
      for (int e = 0; e < 4; ++e) s4 += av[e] * wv[e];
    }
    out[b * HD + n] = fmaxf(s4, 0.f);
  }
}

// ---------------------------------------------------------------------------
extern "C" void kernel_launch(void* const* d_in, const int* in_sizes, int n_in,
                              void* d_out, int out_size, void* d_ws, size_t ws_size,
                              hipStream_t stream)
{
  (void)in_sizes; (void)n_in; (void)out_size; (void)ws_size;
  const float* embed = (const float*)d_in[0];
  const float* Wf  = (const float*)d_in[1];
  const float* bf_ = (const float*)d_in[2];
  const float* b_f = (const float*)d_in[3];
  const float* Wi  = (const float*)d_in[4];
  const float* bi_ = (const float*)d_in[5];
  const float* b_i = (const float*)d_in[6];
  const float* Wu  = (const float*)d_in[7];
  const float* bu_ = (const float*)d_in[8];
  const float* b_u = (const float*)d_in[9];
  const float* Wo  = (const float*)d_in[10];
  const float* bo_ = (const float*)d_in[11];
  const float* b_o = (const float*)d_in[12];
  const float* W1  = (const float*)d_in[13];
  const float* bl1 = (const float*)d_in[14];
  const float* W2  = (const float*)d_in[15];
  const float* bl2 = (const float*)d_in[16];
  const float* W3  = (const float*)d_in[17];
  const float* bl3 = (const float*)d_in[18];
  const float* W4  = (const float*)d_in[19];
  const float* bl4 = (const float*)d_in[20];

  char* ws = (char*)d_ws;
  _Float16* Wh   = (_Float16*)(ws);                 // 1,048,576 B
  float* bsum    = (float*)(ws + 1048576);          // 4 KB
  float* bias2   = (float*)(ws + 1052672);          // 4 KB
  float* cleaf2  = (float*)(ws + 1056768);          // 1 KB
  _Float16* hr   = (_Float16*)(ws + 1057792);       // 64 KB -> end 1,123,328
  _Float16* esum = (_Float16*)(ws + 1123328);       // 33,488,896 B -> 34,612,224
  _Float16* HsA  = (_Float16*)(ws + 34612224);      // 8,388,608 -> 43,000,832
  float* CsA     = (float*)(ws + 43000832);         // 16,777,216 -> 59,778,048
  _Float16* HsB  = (_Float16*)(ws + 59778048);      // 4,194,304 -> 63,972,352
  float* CsB     = (float*)(ws + 63972352);         // 8,388,608 -> 72,360,960

  prep_kernel<<<dim3(16), dim3(256), 0, stream>>>(bf_, b_f, bi_, b_i, bu_, b_u, bo_, b_o,
                                                  Wf, Wi, Wu, Wo, bsum, bias2, cleaf2);
  wcvt_kernel<<<dim3(512), dim3(256), 0, stream>>>(Wf, Wi, Wu, Wo, Wh);
  esum_kernel<<<dim3(64, 128), dim3(256), 0, stream>>>(embed, esum);

  _Float16* hbufs[2] = {HsA, HsB};
  float* cbufs[2] = {CsA, CsB};
  int pp = 0;
  const _Float16* hin = nullptr;
  const float* cin = cleaf2;
  for (int l = 8; l >= 0; --l) {
    const int leaf = (l == 8);
    const int fin = (l == 0);
    _Float16* hout = fin ? hr : hbufs[pp];
    float* cout = cbufs[pp];
    dim3 grid(8, 1 << l);
    level_kernel<<<grid, dim3(256), 0, stream>>>(hin, cin, esum, Wh,
                                                 leaf ? bias2 : bsum,
                                                 hout, cout, l, leaf, fin);
    hin = hbufs[pp];
    cin = cbufs[pp];
    pp ^= 1;
  }

  head_all_kernel<<<dim3(128), dim3(256), 0, stream>>>(hr, W1, bl1, W2, bl2, W3, bl3,
                                                       W4, bl4, (float*)d_out);
}